// Round 4
// baseline (4005.944 us; speedup 1.0000x reference)
//
#include <hip/hip_runtime.h>

#define NN 4096
#define NPOINTS 1024
#define NSAMP 32
#define MROWS (16*NPOINTS*NSAMP)      // 524288
#define OUT2_OFF (16*NPOINTS*3)       // 49152
#define EPSF 1e-5f
#define SITERS 4                      // row-tiles per stage block (512 blocks x 256 thr x 4)

// ---------- bf16 helpers ----------
__device__ __forceinline__ float bflo(unsigned int u){ union{unsigned int i; float f;} v; v.i = u << 16; return v.f; }
__device__ __forceinline__ float bfhi(unsigned int u){ union{unsigned int i; float f;} v; v.i = u & 0xffff0000u; return v.f; }
__device__ __forceinline__ unsigned short f2bf(float f){
  union{float f; unsigned int i;} v; v.f = f;
  unsigned int r = v.i + 0x7fffu + ((v.i >> 16) & 1u);
  return (unsigned short)(r >> 16);
}

// ---------- FPS: 1024 thr x 4 pts, u64-key argmax, single barrier/iter ----------
// key = (float_bits(d) << 32) | ~idx : d>=0 -> bits order-monotone;
// u64 max == (max d, tie -> min idx) == jnp.argmax first-occurrence.
__global__ __launch_bounds__(1024) void k_fps(const float* __restrict__ xyz,
    float* __restrict__ nxyz, float* __restrict__ out){
  __shared__ float xs[NN], ys[NN], zs[NN];
  __shared__ unsigned long long wbest[2][16];
  const int b = blockIdx.x, t = threadIdx.x;
  const float* xb = xyz + (size_t)b*NN*3;
  for (int j = t; j < NN; j += 1024){
    xs[j] = xb[j*3+0]; ys[j] = xb[j*3+1]; zs[j] = xb[j*3+2];
  }
  __syncthreads();
  float px[4], py[4], pz[4], pd[4];
  #pragma unroll
  for (int j=0;j<4;j++){ int i=j*1024+t; px[j]=xs[i]; py[j]=ys[i]; pz[j]=zs[i]; pd[j]=1e10f; }
  int cur = 0;
  const int lane = t & 63, wv = t >> 6;
  for (int it=0; it<NPOINTS; ++it){
    float lx = xs[cur], ly = ys[cur], lz = zs[cur];
    if (t == 0){
      int o = (b*NPOINTS + it)*3;
      nxyz[o]=lx; nxyz[o+1]=ly; nxyz[o+2]=lz;
      out[o]=lx;  out[o+1]=ly;  out[o+2]=lz;
    }
    float bv = -1.0f; int bi = 0;
    #pragma unroll
    for (int j=0;j<4;j++){
      float dx = __fsub_rn(px[j], lx);
      float dy = __fsub_rn(py[j], ly);
      float dz = __fsub_rn(pz[j], lz);
      float d  = __fadd_rn(__fadd_rn(__fmul_rn(dx,dx), __fmul_rn(dy,dy)), __fmul_rn(dz,dz));
      float nd = fminf(pd[j], d);
      pd[j] = nd;
      if (nd > bv){ bv = nd; bi = j*1024 + t; }   // strict > : first occurrence within thread
    }
    unsigned long long key = ((unsigned long long)__float_as_uint(bv) << 32)
                           | (unsigned long long)(0xFFFFFFFFu - (unsigned)bi);
    #pragma unroll
    for (int off=32; off>=1; off>>=1){
      unsigned long long ok = __shfl_xor(key, off, 64);
      if (ok > key) key = ok;
    }
    if (lane == 0) wbest[it & 1][wv] = key;
    __syncthreads();
    unsigned long long best = wbest[it & 1][0];
    #pragma unroll
    for (int w=1; w<16; w++){
      unsigned long long ok = wbest[it & 1][w];
      if (ok > best) best = ok;
    }
    cur = (int)(0xFFFFFFFFu - (unsigned)(best & 0xFFFFFFFFull));
  }
}

// ---------- Ball query: first-32 in-ball indices; R2 = f32(0.04) exactly ----------
__global__ __launch_bounds__(64) void k_ball(const float* __restrict__ xyz,
    const float* __restrict__ nxyz, int* __restrict__ ball_idx){
  const int g = blockIdx.x;           // 256 blocks x 64 threads
  const int b = g >> 4;
  const int p = ((g & 15) << 6) + threadIdx.x;
  const float* xb = xyz + (size_t)b*NN*3;
  const int co = (b*NPOINTS + p)*3;
  const float cx = nxyz[co], cy = nxyz[co+1], cz = nxyz[co+2];
  const int base = (b*NPOINTS + p)*NSAMP;
  const float R2 = 0.04f;
  int cnt = 0, first = 0;
  for (int i = 0; i < NN; ++i){
    float lx = xb[i*3+0], ly = xb[i*3+1], lz = xb[i*3+2];   // wave-uniform -> s_load
    float dx = __fsub_rn(cx, lx);
    float dy = __fsub_rn(cy, ly);
    float dz = __fsub_rn(cz, lz);
    float d2 = __fadd_rn(__fadd_rn(__fmul_rn(dx,dx), __fmul_rn(dy,dy)), __fmul_rn(dz,dz));
    if (d2 < R2 && cnt < NSAMP){
      ball_idx[base + cnt] = i;
      if (cnt == 0) first = i;
      cnt++;
    }
    if ((i & 255) == 255){
      if (__ballot(cnt < NSAMP) == 0ULL) break;
    }
  }
  for (int k = cnt; k < NSAMP; ++k) ball_idx[base + k] = first;
}

// ---------- weight transposes ----------
__global__ __launch_bounds__(256) void k_wt(const float* __restrict__ W1, const float* __restrict__ W2,
    const float* __restrict__ W3, float* __restrict__ W1T, float* __restrict__ W2T, float* __restrict__ W3T){
  int t = blockIdx.x*256 + threadIdx.x;   // 32 blocks
  if (t < 67*64){ int c = t >> 6, o = t & 63;  W1T[t] = W1[o*67 + c]; }
  if (t < 64*64){ int c = t >> 6, o = t & 63;  W2T[t] = W2[o*64 + c]; }
  if (t < 64*128){ int c = t >> 7, o = t & 127; W3T[t] = W3[o*64 + c]; }
}

// ---------- features (B,64,N) fp32 -> featT (B,N,64) bf16 ----------
__global__ __launch_bounds__(256) void k_ft(const float* __restrict__ feat, unsigned short* __restrict__ featT){
  __shared__ float tile[64][65];
  const int b = blockIdx.x >> 6, n0 = (blockIdx.x & 63) << 6;
  const int t = threadIdx.x;
  const int nl = t & 63, cb = t >> 6;
  #pragma unroll
  for (int k=0;k<16;k++){
    int c = cb + (k<<2);
    tile[c][nl] = feat[((size_t)(b*64 + c))*NN + n0 + nl];
  }
  __syncthreads();
  #pragma unroll
  for (int k=0;k<16;k++){
    int nl2 = cb + (k<<2);
    featT[((size_t)(b*NN) + n0 + nl2)*64 + nl] = f2bf(tile[nl][nl2]);
  }
}

// ---------- row producers ----------
__device__ __forceinline__ void gather_y1(int r,
    const float* __restrict__ xyz, const unsigned short* __restrict__ featT,
    const float* __restrict__ nxyz, const int* __restrict__ ball_idx,
    const float* __restrict__ W1T, float* __restrict__ y)
{
  const int b = r >> 15;
  const int p = (r >> 5) & (NPOINTS-1);
  const int i = ball_idx[r];
  const int co = (b*NPOINTS + p)*3;
  const float* xp = xyz + ((size_t)(b*NN + i))*3;
  const float h0 = __fsub_rn(xp[0], nxyz[co]);
  const float h1 = __fsub_rn(xp[1], nxyz[co+1]);
  const float h2 = __fsub_rn(xp[2], nxyz[co+2]);
  #pragma unroll
  for (int o=0;o<64;o++) y[o] = h0 * W1T[o];
  #pragma unroll
  for (int o=0;o<64;o++) y[o] = fmaf(h1, W1T[64+o], y[o]);
  #pragma unroll
  for (int o=0;o<64;o++) y[o] = fmaf(h2, W1T[128+o], y[o]);
  const uint4* fp = (const uint4*)(featT + ((size_t)(b*NN + i))*64);
  #pragma unroll
  for (int c8=0;c8<8;c8++){
    const uint4 u = fp[c8];
    float fv[8];
    fv[0]=bflo(u.x); fv[1]=bfhi(u.x); fv[2]=bflo(u.y); fv[3]=bfhi(u.y);
    fv[4]=bflo(u.z); fv[5]=bfhi(u.z); fv[6]=bflo(u.w); fv[7]=bfhi(u.w);
    const float* wb = W1T + (3 + c8*8)*64;
    #pragma unroll
    for (int k=0;k<8;k++){
      #pragma unroll
      for (int o=0;o<64;o++) y[o] = fmaf(fv[k], wb[k*64+o], y[o]);
    }
  }
}

__device__ __forceinline__ void load_act(const unsigned short* __restrict__ act, int r, float* __restrict__ y){
  const uint4* p = (const uint4*)(act + (size_t)r*64);
  #pragma unroll
  for (int j=0;j<8;j++){
    uint4 u = p[j];
    y[j*8+0]=bflo(u.x); y[j*8+1]=bfhi(u.x); y[j*8+2]=bflo(u.y); y[j*8+3]=bfhi(u.y);
    y[j*8+4]=bflo(u.z); y[j*8+5]=bfhi(u.z); y[j*8+6]=bflo(u.w); y[j*8+7]=bfhi(u.w);
  }
}

__device__ __forceinline__ void store_act(unsigned short* __restrict__ act, int r, const float* __restrict__ y){
  uint4* row = (uint4*)(act + (size_t)r*64);
  #pragma unroll
  for (int j=0;j<8;j++){
    union { uint4 u; unsigned short h[8]; } pk;
    #pragma unroll
    for (int k=0;k<8;k++) pk.h[k] = f2bf(y[j*8+k]);
    row[j] = pk.u;
  }
}

__device__ __forceinline__ void bnrelu64(float* __restrict__ y,
    const float* __restrict__ sc, const float* __restrict__ sh){
  #pragma unroll
  for (int o=0;o<64;o++) y[o] = fmaxf(0.f, fmaf(y[o], sc[o], sh[o]));
}

template<int LDW>
__device__ __forceinline__ void gemm64(const float* __restrict__ a, const float* __restrict__ WT,
                                       float* __restrict__ out){
  #pragma unroll
  for (int o=0;o<64;o++) out[o] = 0.f;
  #pragma unroll 4
  for (int c=0;c<64;c++){
    const float av = a[c];
    const float* wb = WT + c*LDW;    // wave-uniform -> s_load
    #pragma unroll
    for (int o=0;o<64;o++) out[o] = fmaf(av, wb[o], out[o]);
  }
}

// ---------- barrier-free per-channel sum/sumsq: XOR-fold across 64 lanes ----------
// DESTROYS y. After: lane l has channel-l sum added to s_acc, sumsq to q_acc.
__device__ __forceinline__ void chan_reduce(float* __restrict__ y, float& s_acc, float& q_acc, int lane){
  const bool up1 = (lane & 32) != 0;
  float q[32];
  #pragma unroll
  for (int j=0;j<32;j++){                 // sumsq step 1 (squares happen here)
    float sendv = up1 ? y[j] : y[j+32];
    float sq = sendv*sendv;
    float rv = __shfl_xor(sq, 32, 64);
    float keep = up1 ? y[j+32] : y[j];
    q[j] = fmaf(keep, keep, rv);
  }
  #pragma unroll
  for (int j=0;j<32;j++){                 // sum step 1
    float sendv = up1 ? y[j] : y[j+32];
    float rv = __shfl_xor(sendv, 32, 64);
    y[j] = (up1 ? y[j+32] : y[j]) + rv;
  }
  #pragma unroll
  for (int off=16; off>=1; off>>=1){
    const bool up = (lane & off) != 0;
    #pragma unroll
    for (int j=0;j<off;j++){
      float sv = up ? y[j] : y[j+off];
      float rv = __shfl_xor(sv, off, 64);
      y[j] = (up ? y[j+off] : y[j]) + rv;
      float sv2 = up ? q[j] : q[j+off];
      float rv2 = __shfl_xor(sv2, off, 64);
      q[j] = (up ? q[j+off] : q[j]) + rv2;
    }
  }
  s_acc += y[0]; q_acc += q[0];
}

// ---------- a2 producer (bn2(relu(...)) applied) ----------
template<int SRC>   // 0=gather chain, 1=from act1, 2=from act2
__device__ __forceinline__ void get_a2(int r,
    const float* xyz, const unsigned short* featT, const float* nxyz, const int* ball,
    const unsigned short* act1, const unsigned short* act2,
    const float* W1T, const float* W2T,
    const float* sc1, const float* sh1, const float* sc2, const float* sh2,
    float* __restrict__ a2)
{
  if (SRC == 2){
    load_act(act2, r, a2);
    bnrelu64(a2, sc2, sh2);
  } else {
    float y[64];
    if (SRC == 1) load_act(act1, r, y);
    else          gather_y1(r, xyz, featT, nxyz, ball, W1T, y);
    bnrelu64(y, sc1, sh1);
    gemm64<64>(y, W2T, a2);
    bnrelu64(a2, sc2, sh2);
  }
}

// ---------- stage 1: gather -> y1 [-> act1] + stats1 ----------
template<bool STORE>
__global__ __launch_bounds__(256) void k_s1(
    const float* __restrict__ xyz, const unsigned short* __restrict__ featT,
    const float* __restrict__ nxyz, const int* __restrict__ ball,
    const float* __restrict__ W1T, unsigned short* __restrict__ act1,
    float* __restrict__ sums)
{
  const int t = threadIdx.x, lane = t & 63, wv = t >> 6;
  float s = 0.f, q = 0.f;
  for (int it=0; it<SITERS; ++it){
    const int r = blockIdx.x*(256*SITERS) + it*256 + t;
    float y[64];
    gather_y1(r, xyz, featT, nxyz, ball, W1T, y);
    if (STORE) store_act(act1, r, y);
    chan_reduce(y, s, q, lane);
  }
  __shared__ float red[4][2][64];
  red[wv][0][lane] = s; red[wv][1][lane] = q;
  __syncthreads();
  if (t < 64){
    float S = red[0][0][lane]+red[1][0][lane]+red[2][0][lane]+red[3][0][lane];
    float Q = red[0][1][lane]+red[1][1][lane]+red[2][1][lane]+red[3][1][lane];
    atomicAdd(&sums[lane], S);
    atomicAdd(&sums[64+lane], Q);
  }
}

// ---------- stage 2: a1 -> y2 [-> act2] + stats2 ----------
template<int SRC, bool STORE>
__global__ __launch_bounds__(256) void k_s2(
    const float* __restrict__ xyz, const unsigned short* __restrict__ featT,
    const float* __restrict__ nxyz, const int* __restrict__ ball,
    const unsigned short* __restrict__ act1,
    const float* __restrict__ W1T, const float* __restrict__ W2T,
    const float* __restrict__ sc1, const float* __restrict__ sh1,
    unsigned short* __restrict__ act2, float* __restrict__ sums)
{
  const int t = threadIdx.x, lane = t & 63, wv = t >> 6;
  float s = 0.f, q = 0.f;
  for (int it=0; it<SITERS; ++it){
    const int r = blockIdx.x*(256*SITERS) + it*256 + t;
    float y[64];
    if (SRC == 1) load_act(act1, r, y);
    else          gather_y1(r, xyz, featT, nxyz, ball, W1T, y);
    bnrelu64(y, sc1, sh1);
    float y2[64];
    gemm64<64>(y, W2T, y2);
    if (STORE) store_act(act2, r, y2);
    chan_reduce(y2, s, q, lane);
  }
  __shared__ float red[4][2][64];
  red[wv][0][lane] = s; red[wv][1][lane] = q;
  __syncthreads();
  if (t < 64){
    float S = red[0][0][lane]+red[1][0][lane]+red[2][0][lane]+red[3][0][lane];
    float Q = red[0][1][lane]+red[1][1][lane]+red[2][1][lane]+red[3][1][lane];
    atomicAdd(&sums[lane], S);
    atomicAdd(&sums[64+lane], Q);
  }
}

// ---------- stage 3: a2 -> y3 (128ch) + stats3 ----------
template<int SRC>
__global__ __launch_bounds__(256) void k_s3(
    const float* __restrict__ xyz, const unsigned short* __restrict__ featT,
    const float* __restrict__ nxyz, const int* __restrict__ ball,
    const unsigned short* __restrict__ act1, const unsigned short* __restrict__ act2,
    const float* __restrict__ W1T, const float* __restrict__ W2T, const float* __restrict__ W3T,
    const float* __restrict__ sc1, const float* __restrict__ sh1,
    const float* __restrict__ sc2, const float* __restrict__ sh2,
    float* __restrict__ sums)
{
  const int t = threadIdx.x, lane = t & 63, wv = t >> 6;
  float slo=0.f, qlo=0.f, shi=0.f, qhi=0.f;
  for (int it=0; it<SITERS; ++it){
    const int r = blockIdx.x*(256*SITERS) + it*256 + t;
    float a2[64];
    get_a2<SRC>(r, xyz, featT, nxyz, ball, act1, act2, W1T, W2T, sc1, sh1, sc2, sh2, a2);
    float y3[64];
    gemm64<128>(a2, W3T, y3);
    chan_reduce(y3, slo, qlo, lane);
    gemm64<128>(a2, W3T + 64, y3);
    chan_reduce(y3, shi, qhi, lane);
  }
  __shared__ float red[4][4][64];
  red[wv][0][lane]=slo; red[wv][1][lane]=shi; red[wv][2][lane]=qlo; red[wv][3][lane]=qhi;
  __syncthreads();
  if (t < 64){
    #pragma unroll
    for (int k=0;k<4;k++){
      float v = red[0][k][lane]+red[1][k][lane]+red[2][k][lane]+red[3][k][lane];
      atomicAdd(&sums[k*64 + lane], v);
    }
  }
}

// ---------- finalize BN scale/shift ----------
template<int C>
__global__ void k_fin(const float* __restrict__ sums,
    const float* __restrict__ g, const float* __restrict__ bv,
    float* __restrict__ scale, float* __restrict__ shift)
{
  const int c = threadIdx.x;
  float m  = sums[c]   * (1.f/(float)MROWS);
  float vv = sums[C+c] * (1.f/(float)MROWS) - m*m;
  float sc = g[c] / sqrtf(vv + EPSF);
  scale[c] = sc;
  shift[c] = bv[c] - m*sc;
}

// ---------- stage 4: a2 -> y3 -> bn3+relu -> max over 32 samples -> (B,128,1024) ----------
template<int SRC>
__global__ __launch_bounds__(64) void k_s4(
    const float* __restrict__ xyz, const unsigned short* __restrict__ featT,
    const float* __restrict__ nxyz, const int* __restrict__ ball,
    const unsigned short* __restrict__ act1, const unsigned short* __restrict__ act2,
    const float* __restrict__ W1T, const float* __restrict__ W2T, const float* __restrict__ W3,
    const float* __restrict__ sc1, const float* __restrict__ sh1,
    const float* __restrict__ sc2, const float* __restrict__ sh2,
    const float* __restrict__ sc3, const float* __restrict__ sh3,
    float* __restrict__ out)
{
  const int t = threadIdx.x;
  const int s = t & 31;
  const int pair = blockIdx.x*2 + (t >> 5);   // (b,p)
  const int r = pair*32 + s;
  float a2[64];
  get_a2<SRC>(r, xyz, featT, nxyz, ball, act1, act2, W1T, W2T, sc1, sh1, sc2, sh2, a2);
  const int b = pair >> 10, p = pair & (NPOINTS-1);
  float* ob = out + OUT2_OFF + ((size_t)b*128)*1024 + p;
  for (int o=0;o<128;o++){
    const float* wr = W3 + o*64;               // wave-uniform -> s_load
    float v = 0.f;
    #pragma unroll
    for (int c=0;c<64;c++) v = fmaf(a2[c], wr[c], v);
    v = fmaxf(0.f, fmaf(v, sc3[o], sh3[o]));
    #pragma unroll
    for (int off=16; off>=1; off>>=1) v = fmaxf(v, __shfl_xor(v, off, 64));
    if (s == 0) ob[(size_t)o*1024] = v;
  }
}

extern "C" void kernel_launch(void* const* d_in, const int* in_sizes, int n_in,
                              void* d_out, int out_size, void* d_ws, size_t ws_size,
                              hipStream_t stream) {
  const float* xyz  = (const float*)d_in[0];
  const float* feat = (const float*)d_in[1];
  const float* W1   = (const float*)d_in[2];
  const float* g1   = (const float*)d_in[3];
  const float* b1   = (const float*)d_in[4];
  const float* W2   = (const float*)d_in[5];
  const float* g2   = (const float*)d_in[6];
  const float* b2   = (const float*)d_in[7];
  const float* W3   = (const float*)d_in[8];
  const float* g3   = (const float*)d_in[9];
  const float* b3   = (const float*)d_in[10];
  float* out = (float*)d_out;
  char* ws = (char*)d_ws;

  // workspace layout: ~10.8 MB base; +67 MB act1 (T1); +67 MB act2 (T2)
  const size_t o_nxyz = 0;                    // 49152 f
  const size_t o_ball = o_nxyz + 196608;      // 524288 i
  const size_t o_w1t  = o_ball + 2097152;     // 4288 f (pad)
  const size_t o_w2t  = o_w1t  + 17408;       // 4096 f
  const size_t o_w3t  = o_w2t  + 16384;       // 8192 f
  const size_t o_bn   = o_w3t  + 32768;       // 6 x 512B
  const size_t o_sum  = o_bn   + 3072;        // sums1(512) sums2(512) sums3(1024)
  const size_t o_ft   = o_sum  + 2048;        // 8 MB bf16
  const size_t o_act1 = o_ft   + (size_t)16*NN*64*2;
  const size_t o_act2 = o_act1 + (size_t)MROWS*64*2;
  const size_t NEED1  = o_act2;                               // ~78 MB
  const size_t NEED2  = o_act2 + (size_t)MROWS*64*2;          // ~145 MB

  float* nxyz   = (float*)(ws + o_nxyz);
  int*   ball   = (int*)  (ws + o_ball);
  float* W1T    = (float*)(ws + o_w1t);
  float* W2T    = (float*)(ws + o_w2t);
  float* W3T    = (float*)(ws + o_w3t);
  float* sc1    = (float*)(ws + o_bn);
  float* sh1    = (float*)(ws + o_bn + 512);
  float* sc2    = (float*)(ws + o_bn + 1024);
  float* sh2    = (float*)(ws + o_bn + 1536);
  float* sc3    = (float*)(ws + o_bn + 2048);
  float* sh3    = (float*)(ws + o_bn + 2560);
  float* sums1  = (float*)(ws + o_sum);
  float* sums2  = (float*)(ws + o_sum + 512);
  float* sums3  = (float*)(ws + o_sum + 1024);
  unsigned short* featT = (unsigned short*)(ws + o_ft);
  unsigned short* act1  = (unsigned short*)(ws + o_act1);
  unsigned short* act2  = (unsigned short*)(ws + o_act2);

  const int tier = (ws_size >= NEED2) ? 2 : (ws_size >= NEED1) ? 1 : 0;

  hipMemsetAsync(ws + o_sum, 0, 2048, stream);

  k_wt  <<<32,   256, 0, stream>>>(W1, W2, W3, W1T, W2T, W3T);
  k_ft  <<<1024, 256, 0, stream>>>(feat, featT);
  k_fps <<<16,  1024, 0, stream>>>(xyz, nxyz, out);
  k_ball<<<256,  64,  0, stream>>>(xyz, nxyz, ball);

  if (tier == 2){
    k_s1<true> <<<512, 256, 0, stream>>>(xyz, featT, nxyz, ball, W1T, act1, sums1);
    k_fin<64>  <<<1, 64, 0, stream>>>(sums1, g1, b1, sc1, sh1);
    k_s2<1,true><<<512, 256, 0, stream>>>(xyz, featT, nxyz, ball, act1, W1T, W2T, sc1, sh1, act2, sums2);
    k_fin<64>  <<<1, 64, 0, stream>>>(sums2, g2, b2, sc2, sh2);
    k_s3<2>    <<<512, 256, 0, stream>>>(xyz, featT, nxyz, ball, act1, act2, W1T, W2T, W3T,
                                         sc1, sh1, sc2, sh2, sums3);
    k_fin<128> <<<1, 128, 0, stream>>>(sums3, g3, b3, sc3, sh3);
    k_s4<2>    <<<8192, 64, 0, stream>>>(xyz, featT, nxyz, ball, act1, act2, W1T, W2T, W3,
                                         sc1, sh1, sc2, sh2, sc3, sh3, out);
  } else if (tier == 1){
    k_s1<true> <<<512, 256, 0, stream>>>(xyz, featT, nxyz, ball, W1T, act1, sums1);
    k_fin<64>  <<<1, 64, 0, stream>>>(sums1, g1, b1, sc1, sh1);
    k_s2<1,false><<<512, 256, 0, stream>>>(xyz, featT, nxyz, ball, act1, W1T, W2T, sc1, sh1, act2, sums2);
    k_fin<64>  <<<1, 64, 0, stream>>>(sums2, g2, b2, sc2, sh2);
    k_s3<1>    <<<512, 256, 0, stream>>>(xyz, featT, nxyz, ball, act1, act2, W1T, W2T, W3T,
                                         sc1, sh1, sc2, sh2, sums3);
    k_fin<128> <<<1, 128, 0, stream>>>(sums3, g3, b3, sc3, sh3);
    k_s4<1>    <<<8192, 64, 0, stream>>>(xyz, featT, nxyz, ball, act1, act2, W1T, W2T, W3,
                                         sc1, sh1, sc2, sh2, sc3, sh3, out);
  } else {
    k_s1<false><<<512, 256, 0, stream>>>(xyz, featT, nxyz, ball, W1T, act1, sums1);
    k_fin<64>  <<<1, 64, 0, stream>>>(sums1, g1, b1, sc1, sh1);
    k_s2<0,false><<<512, 256, 0, stream>>>(xyz, featT, nxyz, ball, act1, W1T, W2T, sc1, sh1, act2, sums2);
    k_fin<64>  <<<1, 64, 0, stream>>>(sums2, g2, b2, sc2, sh2);
    k_s3<0>    <<<512, 256, 0, stream>>>(xyz, featT, nxyz, ball, act1, act2, W1T, W2T, W3T,
                                         sc1, sh1, sc2, sh2, sums3);
    k_fin<128> <<<1, 128, 0, stream>>>(sums3, g3, b3, sc3, sh3);
    k_s4<0>    <<<8192, 64, 0, stream>>>(xyz, featT, nxyz, ball, act1, act2, W1T, W2T, W3,
                                         sc1, sh1, sc2, sh2, sc3, sh3, out);
  }
}

// Round 5
// 3492.785 us; speedup vs baseline: 1.1469x; 1.1469x over previous
//
#include <hip/hip_runtime.h>

#define NN 4096
#define NPOINTS 1024
#define NSAMP 32
#define MROWS (16*NPOINTS*NSAMP)      // 524288
#define OUT2_OFF (16*NPOINTS*3)       // 49152
#define EPSF 1e-5f
#define SITERS 4                      // row-tiles per stage block (512 blocks x 256 thr x 4)

// ---------- bf16 helpers ----------
__device__ __forceinline__ float bflo(unsigned int u){ union{unsigned int i; float f;} v; v.i = u << 16; return v.f; }
__device__ __forceinline__ float bfhi(unsigned int u){ union{unsigned int i; float f;} v; v.i = u & 0xffff0000u; return v.f; }
__device__ __forceinline__ unsigned short f2bf(float f){
  union{float f; unsigned int i;} v; v.f = f;
  unsigned int r = v.i + 0x7fffu + ((v.i >> 16) & 1u);
  return (unsigned short)(r >> 16);
}

// ---------- FPS: 512 thr x 8 pts, u64-key argmax, single barrier/iter ----------
// key = (float_bits(d) << 32) | ~idx : d>=0 -> bits order-monotone;
// u64 max == (max d, tie -> min idx) == jnp.argmax first-occurrence.
__global__ __launch_bounds__(512) void k_fps(const float* __restrict__ xyz,
    float* __restrict__ nxyz, float* __restrict__ out){
  __shared__ float xs[NN], ys[NN], zs[NN];
  __shared__ unsigned long long wbest[2][8];
  const int b = blockIdx.x, t = threadIdx.x;
  const float* xb = xyz + (size_t)b*NN*3;
  for (int j = t; j < NN; j += 512){
    xs[j] = xb[j*3+0]; ys[j] = xb[j*3+1]; zs[j] = xb[j*3+2];
  }
  __syncthreads();
  float px[8], py[8], pz[8], pd[8];
  #pragma unroll
  for (int j=0;j<8;j++){ int i=j*512+t; px[j]=xs[i]; py[j]=ys[i]; pz[j]=zs[i]; pd[j]=1e10f; }
  int cur = 0;
  const int lane = t & 63, wv = t >> 6;
  for (int it=0; it<NPOINTS; ++it){
    float lx = xs[cur], ly = ys[cur], lz = zs[cur];
    if (t == 0){
      int o = (b*NPOINTS + it)*3;
      nxyz[o]=lx; nxyz[o+1]=ly; nxyz[o+2]=lz;
      out[o]=lx;  out[o+1]=ly;  out[o+2]=lz;
    }
    float bv = -1.0f; int bi = 0;
    #pragma unroll
    for (int j=0;j<8;j++){
      float dx = __fsub_rn(px[j], lx);
      float dy = __fsub_rn(py[j], ly);
      float dz = __fsub_rn(pz[j], lz);
      float d  = __fadd_rn(__fadd_rn(__fmul_rn(dx,dx), __fmul_rn(dy,dy)), __fmul_rn(dz,dz));
      float nd = fminf(pd[j], d);
      pd[j] = nd;
      if (nd > bv){ bv = nd; bi = j*512 + t; }   // strict > : first occurrence within thread
    }
    unsigned long long key = ((unsigned long long)__float_as_uint(bv) << 32)
                           | (unsigned long long)(0xFFFFFFFFu - (unsigned)bi);
    #pragma unroll
    for (int off=32; off>=1; off>>=1){
      unsigned long long ok = __shfl_xor(key, off, 64);
      if (ok > key) key = ok;
    }
    if (lane == 0) wbest[it & 1][wv] = key;
    __syncthreads();
    unsigned long long best = wbest[it & 1][0];
    #pragma unroll
    for (int w=1; w<8; w++){
      unsigned long long ok = wbest[it & 1][w];
      if (ok > best) best = ok;
    }
    cur = (int)(0xFFFFFFFFu - (unsigned)(best & 0xFFFFFFFFull));
  }
}

// ---------- Ball query: first-32 in-ball indices; R2 = f32(0.04) exactly ----------
__global__ __launch_bounds__(64) void k_ball(const float* __restrict__ xyz,
    const float* __restrict__ nxyz, int* __restrict__ ball_idx){
  const int g = blockIdx.x;           // 256 blocks x 64 threads
  const int b = g >> 4;
  const int p = ((g & 15) << 6) + threadIdx.x;
  const float* xb = xyz + (size_t)b*NN*3;
  const int co = (b*NPOINTS + p)*3;
  const float cx = nxyz[co], cy = nxyz[co+1], cz = nxyz[co+2];
  const int base = (b*NPOINTS + p)*NSAMP;
  const float R2 = 0.04f;
  int cnt = 0, first = 0;
  for (int i = 0; i < NN; ++i){
    float lx = xb[i*3+0], ly = xb[i*3+1], lz = xb[i*3+2];   // wave-uniform -> s_load
    float dx = __fsub_rn(cx, lx);
    float dy = __fsub_rn(cy, ly);
    float dz = __fsub_rn(cz, lz);
    float d2 = __fadd_rn(__fadd_rn(__fmul_rn(dx,dx), __fmul_rn(dy,dy)), __fmul_rn(dz,dz));
    if (d2 < R2 && cnt < NSAMP){
      ball_idx[base + cnt] = i;
      if (cnt == 0) first = i;
      cnt++;
    }
    if ((i & 255) == 255){
      if (__ballot(cnt < NSAMP) == 0ULL) break;
    }
  }
  for (int k = cnt; k < NSAMP; ++k) ball_idx[base + k] = first;
}

// ---------- weight transposes ----------
__global__ __launch_bounds__(256) void k_wt(const float* __restrict__ W1, const float* __restrict__ W2,
    const float* __restrict__ W3, float* __restrict__ W1T, float* __restrict__ W2T, float* __restrict__ W3T){
  int t = blockIdx.x*256 + threadIdx.x;   // 32 blocks
  if (t < 67*64){ int c = t >> 6, o = t & 63;  W1T[t] = W1[o*67 + c]; }
  if (t < 64*64){ int c = t >> 6, o = t & 63;  W2T[t] = W2[o*64 + c]; }
  if (t < 64*128){ int c = t >> 7, o = t & 127; W3T[t] = W3[o*64 + c]; }
}

// ---------- features (B,64,N) fp32 -> featT (B,N,64) bf16 ----------
__global__ __launch_bounds__(256) void k_ft(const float* __restrict__ feat, unsigned short* __restrict__ featT){
  __shared__ float tile[64][65];
  const int b = blockIdx.x >> 6, n0 = (blockIdx.x & 63) << 6;
  const int t = threadIdx.x;
  const int nl = t & 63, cb = t >> 6;
  #pragma unroll
  for (int k=0;k<16;k++){
    int c = cb + (k<<2);
    tile[c][nl] = feat[((size_t)(b*64 + c))*NN + n0 + nl];
  }
  __syncthreads();
  #pragma unroll
  for (int k=0;k<16;k++){
    int nl2 = cb + (k<<2);
    featT[((size_t)(b*NN) + n0 + nl2)*64 + nl] = f2bf(tile[nl][nl2]);
  }
}

// ---------- row producers ----------
__device__ __forceinline__ void gather_y1(int r,
    const float* __restrict__ xyz, const unsigned short* __restrict__ featT,
    const float* __restrict__ nxyz, const int* __restrict__ ball_idx,
    const float* __restrict__ W1T, float* __restrict__ y)
{
  const int b = r >> 15;
  const int p = (r >> 5) & (NPOINTS-1);
  const int i = ball_idx[r];
  const int co = (b*NPOINTS + p)*3;
  const float* xp = xyz + ((size_t)(b*NN + i))*3;
  const float h0 = __fsub_rn(xp[0], nxyz[co]);
  const float h1 = __fsub_rn(xp[1], nxyz[co+1]);
  const float h2 = __fsub_rn(xp[2], nxyz[co+2]);
  #pragma unroll
  for (int o=0;o<64;o++) y[o] = h0 * W1T[o];
  #pragma unroll
  for (int o=0;o<64;o++) y[o] = fmaf(h1, W1T[64+o], y[o]);
  #pragma unroll
  for (int o=0;o<64;o++) y[o] = fmaf(h2, W1T[128+o], y[o]);
  const uint4* fp = (const uint4*)(featT + ((size_t)(b*NN + i))*64);
  #pragma unroll
  for (int c8=0;c8<8;c8++){
    const uint4 u = fp[c8];
    float fv[8];
    fv[0]=bflo(u.x); fv[1]=bfhi(u.x); fv[2]=bflo(u.y); fv[3]=bfhi(u.y);
    fv[4]=bflo(u.z); fv[5]=bfhi(u.z); fv[6]=bflo(u.w); fv[7]=bfhi(u.w);
    const float* wb = W1T + (3 + c8*8)*64;
    #pragma unroll
    for (int k=0;k<8;k++){
      #pragma unroll
      for (int o=0;o<64;o++) y[o] = fmaf(fv[k], wb[k*64+o], y[o]);
    }
  }
}

__device__ __forceinline__ void load_act(const unsigned short* __restrict__ act, int r, float* __restrict__ y){
  const uint4* p = (const uint4*)(act + (size_t)r*64);
  #pragma unroll
  for (int j=0;j<8;j++){
    uint4 u = p[j];
    y[j*8+0]=bflo(u.x); y[j*8+1]=bfhi(u.x); y[j*8+2]=bflo(u.y); y[j*8+3]=bfhi(u.y);
    y[j*8+4]=bflo(u.z); y[j*8+5]=bfhi(u.z); y[j*8+6]=bflo(u.w); y[j*8+7]=bfhi(u.w);
  }
}

__device__ __forceinline__ void store_act(unsigned short* __restrict__ act, int r, const float* __restrict__ y){
  uint4* row = (uint4*)(act + (size_t)r*64);
  #pragma unroll
  for (int j=0;j<8;j++){
    union { uint4 u; unsigned short h[8]; } pk;
    #pragma unroll
    for (int k=0;k<8;k++) pk.h[k] = f2bf(y[j*8+k]);
    row[j] = pk.u;
  }
}

__device__ __forceinline__ void bnrelu64(float* __restrict__ y,
    const float* __restrict__ sc, const float* __restrict__ sh){
  #pragma unroll
  for (int o=0;o<64;o++) y[o] = fmaxf(0.f, fmaf(y[o], sc[o], sh[o]));
}

template<int LDW>
__device__ __forceinline__ void gemm64(const float* __restrict__ a, const float* __restrict__ WT,
                                       float* __restrict__ out){
  #pragma unroll
  for (int o=0;o<64;o++) out[o] = 0.f;
  #pragma unroll 4
  for (int c=0;c<64;c++){
    const float av = a[c];
    const float* wb = WT + c*LDW;    // wave-uniform -> s_load
    #pragma unroll
    for (int o=0;o<64;o++) out[o] = fmaf(av, wb[o], out[o]);
  }
}

// ---------- barrier-free per-channel sum/sumsq: XOR-fold across 64 lanes ----------
// DESTROYS y. After: lane l has channel-l sum added to s_acc, sumsq to q_acc.
__device__ __forceinline__ void chan_reduce(float* __restrict__ y, float& s_acc, float& q_acc, int lane){
  const bool up1 = (lane & 32) != 0;
  float q[32];
  #pragma unroll
  for (int j=0;j<32;j++){                 // sumsq step 1 (squares happen here)
    float sendv = up1 ? y[j] : y[j+32];
    float sq = sendv*sendv;
    float rv = __shfl_xor(sq, 32, 64);
    float keep = up1 ? y[j+32] : y[j];
    q[j] = fmaf(keep, keep, rv);
  }
  #pragma unroll
  for (int j=0;j<32;j++){                 // sum step 1
    float sendv = up1 ? y[j] : y[j+32];
    float rv = __shfl_xor(sendv, 32, 64);
    y[j] = (up1 ? y[j+32] : y[j]) + rv;
  }
  #pragma unroll
  for (int off=16; off>=1; off>>=1){
    const bool up = (lane & off) != 0;
    #pragma unroll
    for (int j=0;j<off;j++){
      float sv = up ? y[j] : y[j+off];
      float rv = __shfl_xor(sv, off, 64);
      y[j] = (up ? y[j+off] : y[j]) + rv;
      float sv2 = up ? q[j] : q[j+off];
      float rv2 = __shfl_xor(sv2, off, 64);
      q[j] = (up ? q[j+off] : q[j]) + rv2;
    }
  }
  s_acc += y[0]; q_acc += q[0];
}

// ---------- a2 producer (bn2(relu(...)) applied) ----------
template<int SRC>   // 0=gather chain, 1=from act1, 2=from act2
__device__ __forceinline__ void get_a2(int r,
    const float* xyz, const unsigned short* featT, const float* nxyz, const int* ball,
    const unsigned short* act1, const unsigned short* act2,
    const float* W1T, const float* W2T,
    const float* sc1, const float* sh1, const float* sc2, const float* sh2,
    float* __restrict__ a2)
{
  if (SRC == 2){
    load_act(act2, r, a2);
    bnrelu64(a2, sc2, sh2);
  } else {
    float y[64];
    if (SRC == 1) load_act(act1, r, y);
    else          gather_y1(r, xyz, featT, nxyz, ball, W1T, y);
    bnrelu64(y, sc1, sh1);
    gemm64<64>(y, W2T, a2);
    bnrelu64(a2, sc2, sh2);
  }
}

// ---------- stage 1: gather -> y1 [-> act1] + stats1 ----------
template<bool STORE>
__global__ __launch_bounds__(256, 2) void k_s1(
    const float* __restrict__ xyz, const unsigned short* __restrict__ featT,
    const float* __restrict__ nxyz, const int* __restrict__ ball,
    const float* __restrict__ W1T, unsigned short* __restrict__ act1,
    float* __restrict__ sums)
{
  const int t = threadIdx.x, lane = t & 63, wv = t >> 6;
  float s = 0.f, q = 0.f;
  for (int it=0; it<SITERS; ++it){
    const int r = blockIdx.x*(256*SITERS) + it*256 + t;
    float y[64];
    gather_y1(r, xyz, featT, nxyz, ball, W1T, y);
    if (STORE) store_act(act1, r, y);
    chan_reduce(y, s, q, lane);
  }
  __shared__ float red[4][2][64];
  red[wv][0][lane] = s; red[wv][1][lane] = q;
  __syncthreads();
  if (t < 64){
    float S = red[0][0][lane]+red[1][0][lane]+red[2][0][lane]+red[3][0][lane];
    float Q = red[0][1][lane]+red[1][1][lane]+red[2][1][lane]+red[3][1][lane];
    atomicAdd(&sums[lane], S);
    atomicAdd(&sums[64+lane], Q);
  }
}

// ---------- stage 2: a1 -> y2 [-> act2] + stats2 ----------
template<int SRC, bool STORE>
__global__ __launch_bounds__(256, 2) void k_s2(
    const float* __restrict__ xyz, const unsigned short* __restrict__ featT,
    const float* __restrict__ nxyz, const int* __restrict__ ball,
    const unsigned short* __restrict__ act1,
    const float* __restrict__ W1T, const float* __restrict__ W2T,
    const float* __restrict__ sc1, const float* __restrict__ sh1,
    unsigned short* __restrict__ act2, float* __restrict__ sums)
{
  const int t = threadIdx.x, lane = t & 63, wv = t >> 6;
  float s = 0.f, q = 0.f;
  for (int it=0; it<SITERS; ++it){
    const int r = blockIdx.x*(256*SITERS) + it*256 + t;
    float y[64];
    if (SRC == 1) load_act(act1, r, y);
    else          gather_y1(r, xyz, featT, nxyz, ball, W1T, y);
    bnrelu64(y, sc1, sh1);
    float y2[64];
    gemm64<64>(y, W2T, y2);
    if (STORE) store_act(act2, r, y2);
    chan_reduce(y2, s, q, lane);
  }
  __shared__ float red[4][2][64];
  red[wv][0][lane] = s; red[wv][1][lane] = q;
  __syncthreads();
  if (t < 64){
    float S = red[0][0][lane]+red[1][0][lane]+red[2][0][lane]+red[3][0][lane];
    float Q = red[0][1][lane]+red[1][1][lane]+red[2][1][lane]+red[3][1][lane];
    atomicAdd(&sums[lane], S);
    atomicAdd(&sums[64+lane], Q);
  }
}

// ---------- stage 3: a2 -> y3 (128ch) + stats3 ----------
template<int SRC>
__global__ __launch_bounds__(256, 2) void k_s3(
    const float* __restrict__ xyz, const unsigned short* __restrict__ featT,
    const float* __restrict__ nxyz, const int* __restrict__ ball,
    const unsigned short* __restrict__ act1, const unsigned short* __restrict__ act2,
    const float* __restrict__ W1T, const float* __restrict__ W2T, const float* __restrict__ W3T,
    const float* __restrict__ sc1, const float* __restrict__ sh1,
    const float* __restrict__ sc2, const float* __restrict__ sh2,
    float* __restrict__ sums)
{
  const int t = threadIdx.x, lane = t & 63, wv = t >> 6;
  float slo=0.f, qlo=0.f, shi=0.f, qhi=0.f;
  for (int it=0; it<SITERS; ++it){
    const int r = blockIdx.x*(256*SITERS) + it*256 + t;
    float a2[64];
    get_a2<SRC>(r, xyz, featT, nxyz, ball, act1, act2, W1T, W2T, sc1, sh1, sc2, sh2, a2);
    float y3[64];
    gemm64<128>(a2, W3T, y3);
    chan_reduce(y3, slo, qlo, lane);
    gemm64<128>(a2, W3T + 64, y3);
    chan_reduce(y3, shi, qhi, lane);
  }
  __shared__ float red[4][4][64];
  red[wv][0][lane]=slo; red[wv][1][lane]=shi; red[wv][2][lane]=qlo; red[wv][3][lane]=qhi;
  __syncthreads();
  if (t < 64){
    #pragma unroll
    for (int k=0;k<4;k++){
      float v = red[0][k][lane]+red[1][k][lane]+red[2][k][lane]+red[3][k][lane];
      atomicAdd(&sums[k*64 + lane], v);
    }
  }
}

// ---------- finalize BN scale/shift ----------
template<int C>
__global__ void k_fin(const float* __restrict__ sums,
    const float* __restrict__ g, const float* __restrict__ bv,
    float* __restrict__ scale, float* __restrict__ shift)
{
  const int c = threadIdx.x;
  float m  = sums[c]   * (1.f/(float)MROWS);
  float vv = sums[C+c] * (1.f/(float)MROWS) - m*m;
  float sc = g[c] / sqrtf(vv + EPSF);
  scale[c] = sc;
  shift[c] = bv[c] - m*sc;
}

// ---------- stage 4: a2 -> y3 -> bn3+relu -> max over 32 samples -> (B,128,1024) ----------
template<int SRC>
__global__ __launch_bounds__(64, 2) void k_s4(
    const float* __restrict__ xyz, const unsigned short* __restrict__ featT,
    const float* __restrict__ nxyz, const int* __restrict__ ball,
    const unsigned short* __restrict__ act1, const unsigned short* __restrict__ act2,
    const float* __restrict__ W1T, const float* __restrict__ W2T, const float* __restrict__ W3,
    const float* __restrict__ sc1, const float* __restrict__ sh1,
    const float* __restrict__ sc2, const float* __restrict__ sh2,
    const float* __restrict__ sc3, const float* __restrict__ sh3,
    float* __restrict__ out)
{
  const int t = threadIdx.x;
  const int s = t & 31;
  const int pair = blockIdx.x*2 + (t >> 5);   // (b,p)
  const int r = pair*32 + s;
  float a2[64];
  get_a2<SRC>(r, xyz, featT, nxyz, ball, act1, act2, W1T, W2T, sc1, sh1, sc2, sh2, a2);
  const int b = pair >> 10, p = pair & (NPOINTS-1);
  float* ob = out + OUT2_OFF + ((size_t)b*128)*1024 + p;
  for (int o=0;o<128;o++){
    const float* wr = W3 + o*64;               // wave-uniform -> s_load
    float v = 0.f;
    #pragma unroll
    for (int c=0;c<64;c++) v = fmaf(a2[c], wr[c], v);
    v = fmaxf(0.f, fmaf(v, sc3[o], sh3[o]));
    #pragma unroll
    for (int off=16; off>=1; off>>=1) v = fmaxf(v, __shfl_xor(v, off, 64));
    if (s == 0) ob[(size_t)o*1024] = v;
  }
}

extern "C" void kernel_launch(void* const* d_in, const int* in_sizes, int n_in,
                              void* d_out, int out_size, void* d_ws, size_t ws_size,
                              hipStream_t stream) {
  const float* xyz  = (const float*)d_in[0];
  const float* feat = (const float*)d_in[1];
  const float* W1   = (const float*)d_in[2];
  const float* g1   = (const float*)d_in[3];
  const float* b1   = (const float*)d_in[4];
  const float* W2   = (const float*)d_in[5];
  const float* g2   = (const float*)d_in[6];
  const float* b2   = (const float*)d_in[7];
  const float* W3   = (const float*)d_in[8];
  const float* g3   = (const float*)d_in[9];
  const float* b3   = (const float*)d_in[10];
  float* out = (float*)d_out;
  char* ws = (char*)d_ws;

  // workspace layout: ~10.8 MB base; +67 MB act1 (T1); +67 MB act2 (T2)
  const size_t o_nxyz = 0;                    // 49152 f
  const size_t o_ball = o_nxyz + 196608;      // 524288 i
  const size_t o_w1t  = o_ball + 2097152;     // 4288 f (pad)
  const size_t o_w2t  = o_w1t  + 17408;       // 4096 f
  const size_t o_w3t  = o_w2t  + 16384;       // 8192 f
  const size_t o_bn   = o_w3t  + 32768;       // 6 x 512B
  const size_t o_sum  = o_bn   + 3072;        // sums1(512) sums2(512) sums3(1024)
  const size_t o_ft   = o_sum  + 2048;        // 8 MB bf16
  const size_t o_act1 = o_ft   + (size_t)16*NN*64*2;
  const size_t o_act2 = o_act1 + (size_t)MROWS*64*2;
  const size_t NEED1  = o_act2;                               // ~78 MB
  const size_t NEED2  = o_act2 + (size_t)MROWS*64*2;          // ~145 MB

  float* nxyz   = (float*)(ws + o_nxyz);
  int*   ball   = (int*)  (ws + o_ball);
  float* W1T    = (float*)(ws + o_w1t);
  float* W2T    = (float*)(ws + o_w2t);
  float* W3T    = (float*)(ws + o_w3t);
  float* sc1    = (float*)(ws + o_bn);
  float* sh1    = (float*)(ws + o_bn + 512);
  float* sc2    = (float*)(ws + o_bn + 1024);
  float* sh2    = (float*)(ws + o_bn + 1536);
  float* sc3    = (float*)(ws + o_bn + 2048);
  float* sh3    = (float*)(ws + o_bn + 2560);
  float* sums1  = (float*)(ws + o_sum);
  float* sums2  = (float*)(ws + o_sum + 512);
  float* sums3  = (float*)(ws + o_sum + 1024);
  unsigned short* featT = (unsigned short*)(ws + o_ft);
  unsigned short* act1  = (unsigned short*)(ws + o_act1);
  unsigned short* act2  = (unsigned short*)(ws + o_act2);

  const int tier = (ws_size >= NEED2) ? 2 : (ws_size >= NEED1) ? 1 : 0;

  hipMemsetAsync(ws + o_sum, 0, 2048, stream);

  k_wt  <<<32,   256, 0, stream>>>(W1, W2, W3, W1T, W2T, W3T);
  k_ft  <<<1024, 256, 0, stream>>>(feat, featT);
  k_fps <<<16,   512, 0, stream>>>(xyz, nxyz, out);
  k_ball<<<256,  64,  0, stream>>>(xyz, nxyz, ball);

  if (tier == 2){
    k_s1<true> <<<512, 256, 0, stream>>>(xyz, featT, nxyz, ball, W1T, act1, sums1);
    k_fin<64>  <<<1, 64, 0, stream>>>(sums1, g1, b1, sc1, sh1);
    k_s2<1,true><<<512, 256, 0, stream>>>(xyz, featT, nxyz, ball, act1, W1T, W2T, sc1, sh1, act2, sums2);
    k_fin<64>  <<<1, 64, 0, stream>>>(sums2, g2, b2, sc2, sh2);
    k_s3<2>    <<<512, 256, 0, stream>>>(xyz, featT, nxyz, ball, act1, act2, W1T, W2T, W3T,
                                         sc1, sh1, sc2, sh2, sums3);
    k_fin<128> <<<1, 128, 0, stream>>>(sums3, g3, b3, sc3, sh3);
    k_s4<2>    <<<8192, 64, 0, stream>>>(xyz, featT, nxyz, ball, act1, act2, W1T, W2T, W3,
                                         sc1, sh1, sc2, sh2, sc3, sh3, out);
  } else if (tier == 1){
    k_s1<true> <<<512, 256, 0, stream>>>(xyz, featT, nxyz, ball, W1T, act1, sums1);
    k_fin<64>  <<<1, 64, 0, stream>>>(sums1, g1, b1, sc1, sh1);
    k_s2<1,false><<<512, 256, 0, stream>>>(xyz, featT, nxyz, ball, act1, W1T, W2T, sc1, sh1, act2, sums2);
    k_fin<64>  <<<1, 64, 0, stream>>>(sums2, g2, b2, sc2, sh2);
    k_s3<1>    <<<512, 256, 0, stream>>>(xyz, featT, nxyz, ball, act1, act2, W1T, W2T, W3T,
                                         sc1, sh1, sc2, sh2, sums3);
    k_fin<128> <<<1, 128, 0, stream>>>(sums3, g3, b3, sc3, sh3);
    k_s4<1>    <<<8192, 64, 0, stream>>>(xyz, featT, nxyz, ball, act1, act2, W1T, W2T, W3,
                                         sc1, sh1, sc2, sh2, sc3, sh3, out);
  } else {
    k_s1<false><<<512, 256, 0, stream>>>(xyz, featT, nxyz, ball, W1T, act1, sums1);
    k_fin<64>  <<<1, 64, 0, stream>>>(sums1, g1, b1, sc1, sh1);
    k_s2<0,false><<<512, 256, 0, stream>>>(xyz, featT, nxyz, ball, act1, W1T, W2T, sc1, sh1, act2, sums2);
    k_fin<64>  <<<1, 64, 0, stream>>>(sums2, g2, b2, sc2, sh2);
    k_s3<0>    <<<512, 256, 0, stream>>>(xyz, featT, nxyz, ball, act1, act2, W1T, W2T, W3T,
                                         sc1, sh1, sc2, sh2, sums3);
    k_fin<128> <<<1, 128, 0, stream>>>(sums3, g3, b3, sc3, sh3);
    k_s4<0>    <<<8192, 64, 0, stream>>>(xyz, featT, nxyz, ball, act1, act2, W1T, W2T, W3,
                                         sc1, sh1, sc2, sh2, sc3, sh3, out);
  }
}

// Round 6
// 3031.366 us; speedup vs baseline: 1.3215x; 1.1522x over previous
//
#include <hip/hip_runtime.h>

#define NN 4096
#define NPOINTS 1024
#define NSAMP 32
#define MROWS (16*NPOINTS*NSAMP)      // 524288
#define OUT2_OFF (16*NPOINTS*3)       // 49152
#define EPSF 1e-5f
#define SITERS 2                      // rows per thread in stage kernels (1024 blk x 256 thr x 2)

// ---------- bf16 helpers ----------
__device__ __forceinline__ float bflo(unsigned int u){ union{unsigned int i; float f;} v; v.i = u << 16; return v.f; }
__device__ __forceinline__ float bfhi(unsigned int u){ union{unsigned int i; float f;} v; v.i = u & 0xffff0000u; return v.f; }
__device__ __forceinline__ unsigned short f2bf(float f){
  union{float f; unsigned int i;} v; v.f = f;
  unsigned int r = v.i + 0x7fffu + ((v.i >> 16) & 1u);
  return (unsigned short)(r >> 16);
}
__device__ __forceinline__ unsigned long long umax64(unsigned long long a, unsigned long long b){
  return a > b ? a : b;
}

// ---------- FPS: 512 thr x 8 pts, u64-key argmax (tree), single barrier/iter ----------
__global__ __launch_bounds__(512) void k_fps(const float* __restrict__ xyz,
    float* __restrict__ nxyz, float* __restrict__ out){
  __shared__ float xs[NN], ys[NN], zs[NN];
  __shared__ unsigned long long wbest[2][8];
  const int b = blockIdx.x, t = threadIdx.x;
  const float* xb = xyz + (size_t)b*NN*3;
  for (int j = t; j < NN; j += 512){
    xs[j] = xb[j*3+0]; ys[j] = xb[j*3+1]; zs[j] = xb[j*3+2];
  }
  __syncthreads();
  float px[8], py[8], pz[8], pd[8];
  #pragma unroll
  for (int j=0;j<8;j++){ int i=j*512+t; px[j]=xs[i]; py[j]=ys[i]; pz[j]=zs[i]; pd[j]=1e10f; }
  int cur = 0;
  const int lane = t & 63, wv = t >> 6;
  for (int it=0; it<NPOINTS; ++it){
    float lx = xs[cur], ly = ys[cur], lz = zs[cur];
    if (t == 0){
      int o = (b*NPOINTS + it)*3;
      nxyz[o]=lx; nxyz[o+1]=ly; nxyz[o+2]=lz;
      out[o]=lx;  out[o+1]=ly;  out[o+2]=lz;
    }
    unsigned long long k[8];
    #pragma unroll
    for (int j=0;j<8;j++){
      float dx = __fsub_rn(px[j], lx);
      float dy = __fsub_rn(py[j], ly);
      float dz = __fsub_rn(pz[j], lz);
      float d  = __fadd_rn(__fadd_rn(__fmul_rn(dx,dx), __fmul_rn(dy,dy)), __fmul_rn(dz,dz));
      float nd = fminf(pd[j], d);
      pd[j] = nd;
      // key embeds ~idx: u64 max == (max d, tie -> min idx) == argmax first-occurrence
      k[j] = ((unsigned long long)__float_as_uint(nd) << 32)
           | (unsigned long long)(0xFFFFFFFFu - (unsigned)(j*512 + t));
    }
    k[0]=umax64(k[0],k[1]); k[2]=umax64(k[2],k[3]);
    k[4]=umax64(k[4],k[5]); k[6]=umax64(k[6],k[7]);
    k[0]=umax64(k[0],k[2]); k[4]=umax64(k[4],k[6]);
    unsigned long long key = umax64(k[0],k[4]);
    #pragma unroll
    for (int off=32; off>=1; off>>=1){
      unsigned long long ok = __shfl_xor(key, off, 64);
      if (ok > key) key = ok;
    }
    if (lane == 0) wbest[it & 1][wv] = key;
    __syncthreads();
    unsigned long long best = wbest[it & 1][0];
    #pragma unroll
    for (int w=1; w<8; w++){
      unsigned long long ok = wbest[it & 1][w];
      if (ok > best) best = ok;
    }
    cur = (int)(0xFFFFFFFFu - (unsigned)(best & 0xFFFFFFFFull));
  }
}

// ---------- Ball query ----------
__global__ __launch_bounds__(64) void k_ball(const float* __restrict__ xyz,
    const float* __restrict__ nxyz, int* __restrict__ ball_idx){
  const int g = blockIdx.x;           // 256 blocks x 64 threads
  const int b = g >> 4;
  const int p = ((g & 15) << 6) + threadIdx.x;
  const float* xb = xyz + (size_t)b*NN*3;
  const int co = (b*NPOINTS + p)*3;
  const float cx = nxyz[co], cy = nxyz[co+1], cz = nxyz[co+2];
  const int base = (b*NPOINTS + p)*NSAMP;
  const float R2 = 0.04f;             // f32(0.04) exactly
  int cnt = 0, first = 0;
  for (int i = 0; i < NN; ++i){
    float lx = xb[i*3+0], ly = xb[i*3+1], lz = xb[i*3+2];   // wave-uniform -> s_load
    float dx = __fsub_rn(cx, lx);
    float dy = __fsub_rn(cy, ly);
    float dz = __fsub_rn(cz, lz);
    float d2 = __fadd_rn(__fadd_rn(__fmul_rn(dx,dx), __fmul_rn(dy,dy)), __fmul_rn(dz,dz));
    if (d2 < R2 && cnt < NSAMP){
      ball_idx[base + cnt] = i;
      if (cnt == 0) first = i;
      cnt++;
    }
    if ((i & 255) == 255){
      if (__ballot(cnt < NSAMP) == 0ULL) break;
    }
  }
  for (int k = cnt; k < NSAMP; ++k) ball_idx[base + k] = first;
}

// ---------- weight transposes: W1T[67][64], W2T[64][64] ----------
__global__ __launch_bounds__(256) void k_wt(const float* __restrict__ W1, const float* __restrict__ W2,
    float* __restrict__ W1T, float* __restrict__ W2T){
  int t = blockIdx.x*256 + threadIdx.x;   // 17 blocks
  if (t < 67*64){ int c = t >> 6, o = t & 63;  W1T[t] = W1[o*67 + c]; }
  if (t < 64*64){ int c = t >> 6, o = t & 63;  W2T[t] = W2[o*64 + c]; }
}

// ---------- features (B,64,N) fp32 -> featT (B,N,64) bf16 ----------
__global__ __launch_bounds__(256) void k_ft(const float* __restrict__ feat, unsigned short* __restrict__ featT){
  __shared__ float tile[64][65];
  const int b = blockIdx.x >> 6, n0 = (blockIdx.x & 63) << 6;
  const int t = threadIdx.x;
  const int nl = t & 63, cb = t >> 6;
  #pragma unroll
  for (int k=0;k<16;k++){
    int c = cb + (k<<2);
    tile[c][nl] = feat[((size_t)(b*64 + c))*NN + n0 + nl];
  }
  __syncthreads();
  #pragma unroll
  for (int k=0;k<16;k++){
    int nl2 = cb + (k<<2);
    featT[((size_t)(b*NN) + n0 + nl2)*64 + nl] = f2bf(tile[nl][nl2]);
  }
}

// ---------- constant-index fold: reduce length-OFF*2 info across lanes ----------
template<int OFF>
__device__ __forceinline__ void fold_step(float* __restrict__ v, int lane){
  const bool up = (lane & OFF) != 0;
  #pragma unroll
  for (int j=0;j<OFF;j++){
    float sv = up ? v[j] : v[j+OFF];
    float rv = __shfl_xor(sv, OFF, 64);
    v[j] = (up ? v[j+OFF] : v[j]) + rv;
  }
}

// per-channel sum/sumsq of a 32-wide vector across 64 lanes.
// After: lane l (l<32; duplicated in l+32) holds channel (l&31) in v[0]/q[0].
__device__ __forceinline__ void chan_reduce32(float* __restrict__ v, float& s_acc, float& q_acc, int lane){
  float q[32];
  #pragma unroll
  for (int j=0;j<32;j++) q[j] = v[j]*v[j];
  #pragma unroll
  for (int j=0;j<32;j++) v[j] += __shfl_xor(v[j], 32, 64);
  #pragma unroll
  for (int j=0;j<32;j++) q[j] += __shfl_xor(q[j], 32, 64);
  fold_step<16>(v, lane); fold_step<16>(q, lane);
  fold_step<8>(v, lane);  fold_step<8>(q, lane);
  fold_step<4>(v, lane);  fold_step<4>(q, lane);
  fold_step<2>(v, lane);  fold_step<2>(q, lane);
  fold_step<1>(v, lane);  fold_step<1>(q, lane);
  s_acc += v[0]; q_acc += q[0];
}

// ---------- row producers (ALL private-array indices compile-time constant) ----------
__device__ __forceinline__ void gather_y1(int r,
    const float* __restrict__ xyz, const unsigned short* __restrict__ featT,
    const float* __restrict__ nxyz, const int* __restrict__ ball_idx,
    const float* __restrict__ W1T, float* __restrict__ y)
{
  const int b = r >> 15;
  const int p = (r >> 5) & (NPOINTS-1);
  const int i = ball_idx[r];
  const int co = (b*NPOINTS + p)*3;
  const float* xp = xyz + ((size_t)(b*NN + i))*3;
  const float h0 = __fsub_rn(xp[0], nxyz[co]);
  const float h1 = __fsub_rn(xp[1], nxyz[co+1]);
  const float h2 = __fsub_rn(xp[2], nxyz[co+2]);
  #pragma unroll
  for (int o=0;o<64;o++) y[o] = h0 * W1T[o];
  #pragma unroll
  for (int o=0;o<64;o++) y[o] = fmaf(h1, W1T[64+o], y[o]);
  #pragma unroll
  for (int o=0;o<64;o++) y[o] = fmaf(h2, W1T[128+o], y[o]);
  const uint4* fp = (const uint4*)(featT + ((size_t)(b*NN + i))*64);
  #pragma unroll
  for (int c8=0;c8<8;c8++){
    const uint4 u = fp[c8];
    float fv[8];
    fv[0]=bflo(u.x); fv[1]=bfhi(u.x); fv[2]=bflo(u.y); fv[3]=bfhi(u.y);
    fv[4]=bflo(u.z); fv[5]=bfhi(u.z); fv[6]=bflo(u.w); fv[7]=bfhi(u.w);
    const float* wb = W1T + (3 + c8*8)*64;
    #pragma unroll
    for (int k=0;k<8;k++){
      #pragma unroll
      for (int o=0;o<64;o++) y[o] = fmaf(fv[k], wb[k*64+o], y[o]);
    }
  }
}

__device__ __forceinline__ void load_act(const unsigned short* __restrict__ act, int r, float* __restrict__ y){
  const uint4* p = (const uint4*)(act + (size_t)r*64);
  #pragma unroll
  for (int j=0;j<8;j++){
    uint4 u = p[j];
    y[j*8+0]=bflo(u.x); y[j*8+1]=bfhi(u.x); y[j*8+2]=bflo(u.y); y[j*8+3]=bfhi(u.y);
    y[j*8+4]=bflo(u.z); y[j*8+5]=bfhi(u.z); y[j*8+6]=bflo(u.w); y[j*8+7]=bfhi(u.w);
  }
}

__device__ __forceinline__ void store_act32(unsigned short* __restrict__ act, int r, int half,
                                            const float* __restrict__ y){
  uint4* row = (uint4*)(act + (size_t)r*64 + half*32);
  #pragma unroll
  for (int j=0;j<4;j++){
    union { uint4 u; unsigned short h[8]; } pk;
    #pragma unroll
    for (int k=0;k<8;k++) pk.h[k] = f2bf(y[j*8+k]);
    row[j] = pk.u;
  }
}

__device__ __forceinline__ void bnrelu64(float* __restrict__ y,
    const float* __restrict__ sc, const float* __restrict__ sh){
  #pragma unroll
  for (int o=0;o<64;o++) y[o] = fmaxf(0.f, fmaf(y[o], sc[o], sh[o]));
}

// out[0..31] = a[0..63] . WT[:, half*32 .. half*32+31]   (fully unrolled, constant idx)
__device__ __forceinline__ void gemm64_32(const float* __restrict__ a, const float* __restrict__ WT,
                                          int half, float* __restrict__ y){
  const float* w0 = WT + half*32;
  #pragma unroll
  for (int o=0;o<32;o++) y[o] = 0.f;
  #pragma unroll
  for (int c=0;c<64;c++){
    const float av = a[c];
    const float* wb = w0 + c*64;
    #pragma unroll
    for (int o=0;o<32;o++) y[o] = fmaf(av, wb[o], y[o]);
  }
}

// out[0..15] = a[0..63] . WT[:, c0 .. c0+15]
__device__ __forceinline__ void gemm64_16(const float* __restrict__ a, const float* __restrict__ WT,
                                          int c0, float* __restrict__ y){
  const float* w0 = WT + c0;
  #pragma unroll
  for (int o=0;o<16;o++) y[o] = 0.f;
  #pragma unroll
  for (int c=0;c<64;c++){
    const float av = a[c];
    const float* wb = w0 + c*64;
    #pragma unroll
    for (int o=0;o<16;o++) y[o] = fmaf(av, wb[o], y[o]);
  }
}

// ---------- stage 1: gather -> y1 halves [-> act] + stats1 ----------
__device__ __forceinline__ void s1_half(float h0, float h1, float h2, const uint4* fp,
    const float* __restrict__ W1T, int half, unsigned short* __restrict__ act, int r, bool store,
    int lane, float& s, float& q){
  float y[32];
  const float* w0 = W1T + half*32;
  #pragma unroll
  for (int o=0;o<32;o++) y[o] = h0 * w0[o];
  #pragma unroll
  for (int o=0;o<32;o++) y[o] = fmaf(h1, w0[64+o], y[o]);
  #pragma unroll
  for (int o=0;o<32;o++) y[o] = fmaf(h2, w0[128+o], y[o]);
  #pragma unroll
  for (int c8=0;c8<8;c8++){
    uint4 u = fp[c8];
    float fv[8];
    fv[0]=bflo(u.x); fv[1]=bfhi(u.x); fv[2]=bflo(u.y); fv[3]=bfhi(u.y);
    fv[4]=bflo(u.z); fv[5]=bfhi(u.z); fv[6]=bflo(u.w); fv[7]=bfhi(u.w);
    const float* wb = w0 + (3 + c8*8)*64;
    #pragma unroll
    for (int k=0;k<8;k++){
      #pragma unroll
      for (int o=0;o<32;o++) y[o] = fmaf(fv[k], wb[k*64+o], y[o]);
    }
  }
  if (store) store_act32(act, r, half, y);
  chan_reduce32(y, s, q, lane);
}

template<bool STORE>
__global__ __launch_bounds__(256, 2) void k_s1(
    const float* __restrict__ xyz, const unsigned short* __restrict__ featT,
    const float* __restrict__ nxyz, const int* __restrict__ ball,
    const float* __restrict__ W1T, unsigned short* __restrict__ act,
    float* __restrict__ sums)
{
  const int t = threadIdx.x, lane = t & 63, wv = t >> 6;
  float s0=0.f, q0=0.f, s1=0.f, q1=0.f;
  for (int it=0; it<SITERS; ++it){
    const int r = blockIdx.x*(256*SITERS) + it*256 + t;
    const int b = r >> 15;
    const int p = (r >> 5) & (NPOINTS-1);
    const int i = ball[r];
    const int co = (b*NPOINTS + p)*3;
    const float* xp = xyz + ((size_t)(b*NN + i))*3;
    const float h0 = __fsub_rn(xp[0], nxyz[co]);
    const float h1 = __fsub_rn(xp[1], nxyz[co+1]);
    const float h2 = __fsub_rn(xp[2], nxyz[co+2]);
    const uint4* fp = (const uint4*)(featT + ((size_t)(b*NN + i))*64);
    s1_half(h0,h1,h2, fp, W1T, 0, act, r, STORE, lane, s0, q0);
    s1_half(h0,h1,h2, fp, W1T, 1, act, r, STORE, lane, s1, q1);
  }
  __shared__ float red[4][4][32];
  if (lane < 32){
    red[wv][0][lane]=s0; red[wv][1][lane]=s1; red[wv][2][lane]=q0; red[wv][3][lane]=q1;
  }
  __syncthreads();
  if (t < 128){
    int k = t >> 5, c = t & 31;
    float v = red[0][k][c]+red[1][k][c]+red[2][k][c]+red[3][k][c];
    atomicAdd(&sums[t], v);    // [sum 0..63 | sumsq 0..63]
  }
}

// ---------- stage 2: y1 -> bn1relu -> y2 halves [-> act in place] + stats2 ----------
__device__ __forceinline__ void s2_half(const float* __restrict__ a1, const float* __restrict__ W2T,
    int half, unsigned short* __restrict__ act, int r, bool store, int lane, float& s, float& q){
  float y[32];
  gemm64_32(a1, W2T, half, y);
  if (store) store_act32(act, r, half, y);
  chan_reduce32(y, s, q, lane);
}

template<bool ACT>
__global__ __launch_bounds__(256, 2) void k_s2(
    const float* __restrict__ xyz, const unsigned short* __restrict__ featT,
    const float* __restrict__ nxyz, const int* __restrict__ ball,
    unsigned short* __restrict__ act,
    const float* __restrict__ W1T, const float* __restrict__ W2T,
    const float* __restrict__ sc1, const float* __restrict__ sh1,
    float* __restrict__ sums)
{
  const int t = threadIdx.x, lane = t & 63, wv = t >> 6;
  float s0=0.f, q0=0.f, s1=0.f, q1=0.f;
  for (int it=0; it<SITERS; ++it){
    const int r = blockIdx.x*(256*SITERS) + it*256 + t;
    float a1[64];
    if (ACT) load_act(act, r, a1);
    else     gather_y1(r, xyz, featT, nxyz, ball, W1T, a1);
    bnrelu64(a1, sc1, sh1);
    s2_half(a1, W2T, 0, act, r, ACT, lane, s0, q0);   // in-place overwrite y1 -> y2
    s2_half(a1, W2T, 1, act, r, ACT, lane, s1, q1);
  }
  __shared__ float red[4][4][32];
  if (lane < 32){
    red[wv][0][lane]=s0; red[wv][1][lane]=s1; red[wv][2][lane]=q0; red[wv][3][lane]=q1;
  }
  __syncthreads();
  if (t < 128){
    int k = t >> 5, c = t & 31;
    float v = red[0][k][c]+red[1][k][c]+red[2][k][c]+red[3][k][c];
    atomicAdd(&sums[t], v);
  }
}

// ---------- finalize BN scale/shift (64-ch stages) ----------
template<int C>
__global__ void k_fin(const float* __restrict__ sums,
    const float* __restrict__ g, const float* __restrict__ bv,
    float* __restrict__ scale, float* __restrict__ shift)
{
  const int c = threadIdx.x;
  float m  = sums[c]   * (1.f/(float)MROWS);
  float vv = sums[C+c] * (1.f/(float)MROWS) - m*m;
  float sc = g[c] / sqrtf(vv + EPSF);
  scale[c] = sc;
  shift[c] = bv[c] - m*sc;
}

// ---------- stage 3: Gram of a2 (G = sum a2 a2^T, 64x64) + colsum ----------
template<bool ACT>
__global__ __launch_bounds__(256) void k_s3g(
    const float* __restrict__ xyz, const unsigned short* __restrict__ featT,
    const float* __restrict__ nxyz, const int* __restrict__ ball,
    const unsigned short* __restrict__ act,
    const float* __restrict__ W1T, const float* __restrict__ W2T,
    const float* __restrict__ sc1, const float* __restrict__ sh1,
    const float* __restrict__ sc2, const float* __restrict__ sh2,
    float* __restrict__ G, float* __restrict__ colsum)
{
  __shared__ float at[64*64];         // 16 KB fp32 a2 tile
  const int t = threadIdx.x;
  const int rr = t >> 2, qq4 = t & 3, c0 = qq4*16;   // loader: row rr, channels c0..c0+15
  const int c1 = (t >> 4) * 4, c2 = (t & 15) * 4;    // compute: 4x4 tile
  float s2v[16], h2v[16];
  #pragma unroll
  for (int k=0;k<16;k++){ s2v[k]=sc2[c0+k]; h2v[k]=sh2[c0+k]; }
  float acc[16];
  #pragma unroll
  for (int k=0;k<16;k++) acc[k]=0.f;
  float cs[4] = {0.f,0.f,0.f,0.f};
  for (int tile=0; tile<16; ++tile){
    const int r = (blockIdx.x*16 + tile)*64 + rr;
    float yv[16];
    if (ACT){
      const uint4* p = (const uint4*)(act + (size_t)r*64 + c0);
      uint4 u0 = p[0], u1 = p[1];
      yv[0]=bflo(u0.x); yv[1]=bfhi(u0.x); yv[2]=bflo(u0.y); yv[3]=bfhi(u0.y);
      yv[4]=bflo(u0.z); yv[5]=bfhi(u0.z); yv[6]=bflo(u0.w); yv[7]=bfhi(u0.w);
      yv[8]=bflo(u1.x); yv[9]=bfhi(u1.x); yv[10]=bflo(u1.y); yv[11]=bfhi(u1.y);
      yv[12]=bflo(u1.z); yv[13]=bfhi(u1.z); yv[14]=bflo(u1.w); yv[15]=bfhi(u1.w);
    } else {
      float y1[64];
      gather_y1(r, xyz, featT, nxyz, ball, W1T, y1);
      bnrelu64(y1, sc1, sh1);
      gemm64_16(y1, W2T, c0, yv);
    }
    #pragma unroll
    for (int k=0;k<16;k++) yv[k] = fmaxf(0.f, fmaf(yv[k], s2v[k], h2v[k]));
    __syncthreads();
    #pragma unroll
    for (int k4=0;k4<4;k4++)
      *(float4*)&at[rr*64 + c0 + k4*4] = make_float4(yv[k4*4],yv[k4*4+1],yv[k4*4+2],yv[k4*4+3]);
    __syncthreads();
    #pragma unroll 8
    for (int r2=0;r2<64;r2++){
      float4 xa = *(const float4*)&at[r2*64 + c1];
      float4 ya = *(const float4*)&at[r2*64 + c2];
      float x[4]  = {xa.x,xa.y,xa.z,xa.w};
      float yy[4] = {ya.x,ya.y,ya.z,ya.w};
      #pragma unroll
      for (int i=0;i<4;i++)
        #pragma unroll
        for (int j=0;j<4;j++) acc[i*4+j] = fmaf(x[i], yy[j], acc[i*4+j]);
      if (t < 16){ cs[0]+=ya.x; cs[1]+=ya.y; cs[2]+=ya.z; cs[3]+=ya.w; }
    }
  }
  #pragma unroll
  for (int i=0;i<4;i++)
    #pragma unroll
    for (int j=0;j<4;j++) atomicAdd(&G[(c1+i)*64 + c2+j], acc[i*4+j]);
  if (t < 16){
    #pragma unroll
    for (int k=0;k<4;k++) atomicAdd(&colsum[c2+k], cs[k]);
  }
}

// ---------- fin3: sc3/sh3 from Gram: sum_o = W3 . colsum ; sumsq_o = w^T G w ----------
__global__ __launch_bounds__(256) void k_fin3(const float* __restrict__ G, const float* __restrict__ colsum,
    const float* __restrict__ W3, const float* __restrict__ g3, const float* __restrict__ b3,
    float* __restrict__ sc3, float* __restrict__ sh3)
{
  const int t = threadIdx.x;          // 256 = 128 o x 2 halves
  const int o = t & 127, half = t >> 7;
  float w[64];
  const float4* wp = (const float4*)(W3 + o*64);
  #pragma unroll
  for (int q=0;q<16;q++){ float4 v = wp[q]; w[q*4]=v.x; w[q*4+1]=v.y; w[q*4+2]=v.z; w[q*4+3]=v.w; }
  float qq = 0.f;
  #pragma unroll
  for (int cc=0; cc<32; cc++){
    const float* Gr = G + (half*32 + cc)*64;    // wave-uniform -> s_load
    float tc = 0.f;
    #pragma unroll
    for (int c2=0;c2<64;c2++) tc = fmaf(Gr[c2], w[c2], tc);
    float wc = half ? w[32+cc] : w[cc];
    qq = fmaf(wc, tc, qq);
  }
  __shared__ float hq[128];
  if (half) hq[o] = qq;
  __syncthreads();
  if (!half){
    qq += hq[o];
    float ss = 0.f;
    #pragma unroll
    for (int c=0;c<64;c++) ss = fmaf(w[c], colsum[c], ss);
    float m  = ss * (1.f/(float)MROWS);
    float vv = qq * (1.f/(float)MROWS) - m*m;
    float sc = g3[o] / sqrtf(vv + EPSF);
    sc3[o] = sc;
    sh3[o] = b3[o] - m*sc;
  }
}

// ---------- stage 4: a2 -> y3 -> bn3+relu -> max over 32 samples -> (B,128,1024) ----------
template<bool ACT>
__global__ __launch_bounds__(64) void k_s4(
    const float* __restrict__ xyz, const unsigned short* __restrict__ featT,
    const float* __restrict__ nxyz, const int* __restrict__ ball,
    const unsigned short* __restrict__ act,
    const float* __restrict__ W1T, const float* __restrict__ W2T, const float* __restrict__ W3,
    const float* __restrict__ sc1, const float* __restrict__ sh1,
    const float* __restrict__ sc2, const float* __restrict__ sh2,
    const float* __restrict__ sc3, const float* __restrict__ sh3,
    float* __restrict__ out)
{
  const int t = threadIdx.x;
  const int s = t & 31;
  const int pair = blockIdx.x*2 + (t >> 5);   // (b,p)
  const int r = pair*32 + s;
  float a2[64];
  if (ACT){
    load_act(act, r, a2);
  } else {
    float y[64];
    gather_y1(r, xyz, featT, nxyz, ball, W1T, y);
    bnrelu64(y, sc1, sh1);
    gemm64_32(y, W2T, 0, a2);
    gemm64_32(y, W2T, 1, a2 + 32);
  }
  bnrelu64(a2, sc2, sh2);
  const int b = pair >> 10, p = pair & (NPOINTS-1);
  float* ob = out + OUT2_OFF + ((size_t)b*128)*1024 + p;
  for (int o=0;o<128;o++){
    const float* wr = W3 + o*64;               // wave-uniform -> s_load
    float v = 0.f;
    #pragma unroll
    for (int c=0;c<64;c++) v = fmaf(a2[c], wr[c], v);
    v = fmaxf(0.f, fmaf(v, sc3[o], sh3[o]));
    #pragma unroll
    for (int off=16; off>=1; off>>=1) v = fmaxf(v, __shfl_xor(v, off, 64));
    if (s == 0) ob[(size_t)o*1024] = v;
  }
}

extern "C" void kernel_launch(void* const* d_in, const int* in_sizes, int n_in,
                              void* d_out, int out_size, void* d_ws, size_t ws_size,
                              hipStream_t stream) {
  const float* xyz  = (const float*)d_in[0];
  const float* feat = (const float*)d_in[1];
  const float* W1   = (const float*)d_in[2];
  const float* g1   = (const float*)d_in[3];
  const float* b1   = (const float*)d_in[4];
  const float* W2   = (const float*)d_in[5];
  const float* g2   = (const float*)d_in[6];
  const float* b2   = (const float*)d_in[7];
  const float* W3   = (const float*)d_in[8];
  const float* g3   = (const float*)d_in[9];
  const float* b3   = (const float*)d_in[10];
  float* out = (float*)d_out;
  char* ws = (char*)d_ws;

  // workspace layout: ~10.8 MB base; +67 MB single act buffer
  const size_t o_nxyz = 0;                    // 49152 f
  const size_t o_ball = o_nxyz + 196608;      // 524288 i
  const size_t o_w1t  = o_ball + 2097152;     // 4288 f (pad to 17408)
  const size_t o_w2t  = o_w1t  + 17408;       // 4096 f
  const size_t o_bn   = o_w2t  + 16384;       // 6 x 512B
  const size_t o_sum  = o_bn   + 3072;        // sums1(128f) sums2(128f) G(4096f) colsum(64f)
  const size_t o_ft   = o_sum  + 17664;       // 8 MB bf16
  const size_t o_act  = o_ft   + (size_t)16*NN*64*2;
  const size_t NEED   = o_act  + (size_t)MROWS*64*2;   // ~88 MB

  float* nxyz   = (float*)(ws + o_nxyz);
  int*   ball   = (int*)  (ws + o_ball);
  float* W1T    = (float*)(ws + o_w1t);
  float* W2T    = (float*)(ws + o_w2t);
  float* sc1    = (float*)(ws + o_bn);
  float* sh1    = (float*)(ws + o_bn + 512);
  float* sc2    = (float*)(ws + o_bn + 1024);
  float* sh2    = (float*)(ws + o_bn + 1536);
  float* sc3    = (float*)(ws + o_bn + 2048);
  float* sh3    = (float*)(ws + o_bn + 2560);
  float* sums1  = (float*)(ws + o_sum);
  float* sums2  = (float*)(ws + o_sum + 512);
  float* G      = (float*)(ws + o_sum + 1024);
  float* colsum = (float*)(ws + o_sum + 17408);
  unsigned short* featT = (unsigned short*)(ws + o_ft);
  unsigned short* act   = (unsigned short*)(ws + o_act);

  const bool useact = (ws_size >= NEED);

  hipMemsetAsync(ws + o_sum, 0, 17664, stream);

  k_wt  <<<17,   256, 0, stream>>>(W1, W2, W1T, W2T);
  k_ft  <<<1024, 256, 0, stream>>>(feat, featT);
  k_fps <<<16,   512, 0, stream>>>(xyz, nxyz, out);
  k_ball<<<256,  64,  0, stream>>>(xyz, nxyz, ball);

  if (useact){
    k_s1<true> <<<1024, 256, 0, stream>>>(xyz, featT, nxyz, ball, W1T, act, sums1);
    k_fin<64>  <<<1, 64, 0, stream>>>(sums1, g1, b1, sc1, sh1);
    k_s2<true> <<<1024, 256, 0, stream>>>(xyz, featT, nxyz, ball, act, W1T, W2T, sc1, sh1, sums2);
    k_fin<64>  <<<1, 64, 0, stream>>>(sums2, g2, b2, sc2, sh2);
    k_s3g<true><<<512, 256, 0, stream>>>(xyz, featT, nxyz, ball, act, W1T, W2T,
                                         sc1, sh1, sc2, sh2, G, colsum);
    k_fin3     <<<1, 256, 0, stream>>>(G, colsum, W3, g3, b3, sc3, sh3);
    k_s4<true> <<<8192, 64, 0, stream>>>(xyz, featT, nxyz, ball, act, W1T, W2T, W3,
                                         sc1, sh1, sc2, sh2, sc3, sh3, out);
  } else {
    k_s1<false> <<<1024, 256, 0, stream>>>(xyz, featT, nxyz, ball, W1T, act, sums1);
    k_fin<64>   <<<1, 64, 0, stream>>>(sums1, g1, b1, sc1, sh1);
    k_s2<false> <<<1024, 256, 0, stream>>>(xyz, featT, nxyz, ball, act, W1T, W2T, sc1, sh1, sums2);
    k_fin<64>   <<<1, 64, 0, stream>>>(sums2, g2, b2, sc2, sh2);
    k_s3g<false><<<512, 256, 0, stream>>>(xyz, featT, nxyz, ball, act, W1T, W2T,
                                          sc1, sh1, sc2, sh2, G, colsum);
    k_fin3      <<<1, 256, 0, stream>>>(G, colsum, W3, g3, b3, sc3, sh3);
    k_s4<false> <<<8192, 64, 0, stream>>>(xyz, featT, nxyz, ball, act, W1T, W2T, W3,
                                          sc1, sh1, sc2, sh2, sc3, sh3, out);
  }
}